// Round 1
// baseline (117.828 us; speedup 1.0000x reference)
//
#include <hip/hip_runtime.h>

// RNN: h_t = tanh(x_t * w_ih + b_ih + b_hh + W_hh h_{t-1});  out = h_T . w_fc + b_fc
// B=4096, T=512, I=1, H=16, O=1.
// Layout: 16 lanes per batch element (lane 'me' owns h[me]); cross-lane via DPP row_ror.

constexpr int T_STEPS = 512;

#define DPP_ROR(r, src) __builtin_amdgcn_update_dpp(0, (src), 0x120 + (r), 0xF, 0xF, false)

__global__ __launch_bounds__(256) void rnn_fused(
    const float* __restrict__ x,
    const float* __restrict__ w_ih,
    const float* __restrict__ w_hh,
    const float* __restrict__ b_ih,
    const float* __restrict__ b_hh,
    const float* __restrict__ w_fc,
    const float* __restrict__ b_fc,
    float* __restrict__ out)
{
    const int tid = blockIdx.x * blockDim.x + threadIdx.x;
    const int b   = tid >> 4;   // batch element
    const int me  = tid & 15;   // hidden unit owned by this lane

    const float wih  = w_ih[me];              // (H, I=1)
    const float bias = b_ih[me] + b_hh[me];
    const float wfc  = w_fc[me];              // (O=1, H)

    // Direction-proof weight gather: rotate each lane's own index through the
    // same DPP control we'll use on h, so wr[r] is w_hh[me][whatever lane DPP
    // actually sources at rotation r]. Correct under either ror convention.
    float wr[16];
    {
        const int base = me << 4;            // w_hh row 'me' (H x H row-major)
        wr[0] = w_hh[base + me];
        #define WSETUP(r) { int s_ = DPP_ROR(r, me); wr[r] = w_hh[base + s_]; }
        WSETUP(1)  WSETUP(2)  WSETUP(3)  WSETUP(4)  WSETUP(5)
        WSETUP(6)  WSETUP(7)  WSETUP(8)  WSETUP(9)  WSETUP(10)
        WSETUP(11) WSETUP(12) WSETUP(13) WSETUP(14) WSETUP(15)
        #undef WSETUP
    }

    const float* xb = x + ((size_t)b << 9);  // x[b, :, 0], T=512 floats, 16B aligned
    float h = 0.0f;

    // One timestep: a0..a3 are 4 independent FMA chains (depth 4) to keep the
    // VALU issue-bound rather than dependency-bound at 1 wave/SIMD.
    #define STEP(xval) {                                                  \
        const int hb = __float_as_int(h);                                 \
        float a0 = fmaf((xval), wih, bias);                               \
        a0 = fmaf(h, wr[0], a0);                                          \
        float a1 = __int_as_float(DPP_ROR(1, hb)) * wr[1];                \
        float a2 = __int_as_float(DPP_ROR(2, hb)) * wr[2];                \
        float a3 = __int_as_float(DPP_ROR(3, hb)) * wr[3];                \
        a0 = fmaf(__int_as_float(DPP_ROR(4,  hb)), wr[4],  a0);           \
        a1 = fmaf(__int_as_float(DPP_ROR(5,  hb)), wr[5],  a1);           \
        a2 = fmaf(__int_as_float(DPP_ROR(6,  hb)), wr[6],  a2);           \
        a3 = fmaf(__int_as_float(DPP_ROR(7,  hb)), wr[7],  a3);           \
        a0 = fmaf(__int_as_float(DPP_ROR(8,  hb)), wr[8],  a0);           \
        a1 = fmaf(__int_as_float(DPP_ROR(9,  hb)), wr[9],  a1);           \
        a2 = fmaf(__int_as_float(DPP_ROR(10, hb)), wr[10], a2);           \
        a3 = fmaf(__int_as_float(DPP_ROR(11, hb)), wr[11], a3);           \
        a0 = fmaf(__int_as_float(DPP_ROR(12, hb)), wr[12], a0);           \
        a1 = fmaf(__int_as_float(DPP_ROR(13, hb)), wr[13], a1);           \
        a2 = fmaf(__int_as_float(DPP_ROR(14, hb)), wr[14], a2);           \
        a3 = fmaf(__int_as_float(DPP_ROR(15, hb)), wr[15], a3);           \
        const float s_ = (a0 + a1) + (a2 + a3);                           \
        /* tanh(s) = 1 - 2/(exp2(s*2*log2e)+1) : 2 trans + 3 VALU */      \
        const float e_ = __builtin_amdgcn_exp2f(s_ * 2.8853900817779268f);\
        const float rc = __builtin_amdgcn_rcpf(e_ + 1.0f);                \
        h = fmaf(-2.0f, rc, 1.0f);                                        \
    }

    // Main T loop, 8 steps per iteration, next block's x prefetched as float4x2
    // so the (L1-resident, 16-lanes-same-address) loads hide under compute.
    float4 cur0 = *reinterpret_cast<const float4*>(xb);
    float4 cur1 = *reinterpret_cast<const float4*>(xb + 4);
    #pragma unroll 1
    for (int tb = 0; tb < T_STEPS; tb += 8) {
        const int nxt = (tb + 8 < T_STEPS) ? (tb + 8) : 0;  // last iter: dummy reload
        const float4 n0 = *reinterpret_cast<const float4*>(xb + nxt);
        const float4 n1 = *reinterpret_cast<const float4*>(xb + nxt + 4);
        STEP(cur0.x) STEP(cur0.y) STEP(cur0.z) STEP(cur0.w)
        STEP(cur1.x) STEP(cur1.y) STEP(cur1.z) STEP(cur1.w)
        cur0 = n0; cur1 = n1;
    }
    #undef STEP

    // out[b] = dot(h_last, w_fc) + b_fc  — reduce across the 16-lane group.
    float v = h * wfc;
    v += __shfl_xor(v, 8);
    v += __shfl_xor(v, 4);
    v += __shfl_xor(v, 2);
    v += __shfl_xor(v, 1);
    if (me == 0) out[b] = v + b_fc[0];
}

extern "C" void kernel_launch(void* const* d_in, const int* in_sizes, int n_in,
                              void* d_out, int out_size, void* d_ws, size_t ws_size,
                              hipStream_t stream) {
    const float* x    = (const float*)d_in[0];
    const float* w_ih = (const float*)d_in[1];
    const float* w_hh = (const float*)d_in[2];
    const float* b_ih = (const float*)d_in[3];
    const float* b_hh = (const float*)d_in[4];
    const float* w_fc = (const float*)d_in[5];
    const float* b_fc = (const float*)d_in[6];
    float* out = (float*)d_out;

    const int B = out_size;                  // 4096
    const int threads = 256;
    const int blocks  = (B * 16) / threads;  // 256 blocks -> 1 per CU, 1 wave/SIMD
    rnn_fused<<<blocks, threads, 0, stream>>>(x, w_ih, w_hh, b_ih, b_hh, w_fc, b_fc, out);
}